// Round 1
// baseline (1499.135 us; speedup 1.0000x reference)
//
#include <hip/hip_runtime.h>
#include <hip/hip_bf16.h>
#include <stdint.h>
#include <stddef.h>

// Problem dims
#define BATCH 1024
#define TSEQ  99      // SEQ_LEN-1 steps
#define HID   256
#define GDIM  1024    // 4*HID
#define EDIM  128
#define VOC   410
#define NT_FC 26      // ceil(410/16) -> padded 416

typedef __attribute__((ext_vector_type(8))) short short8;
typedef __attribute__((ext_vector_type(4))) float floatx4;

__device__ __forceinline__ short f2bf(float x) {
    union { float f; uint32_t u; } v; v.f = x;
    uint32_t r = (v.u + 0x7fffu + ((v.u >> 16) & 1u)) >> 16;
    return (short)r;
}

// ---------------------------------------------------------------------------
// enc[b][h] = b_enc[h] + sum_k encoder_out[b][k] * W_enc[h][k]
// grid 128 blocks x 256 thr, 8 batch rows per block
__global__ void k_enc(const float* __restrict__ x, const float* __restrict__ W,
                      const float* __restrict__ bias, float* __restrict__ enc) {
    __shared__ float xl[8 * 256];
    const int tid = threadIdx.x;
    const int b0 = blockIdx.x * 8;
#pragma unroll
    for (int i = 0; i < 8; ++i) xl[i * 256 + tid] = x[(b0 + i) * 256 + tid];
    __syncthreads();
    const int h = tid;
    float acc[8];
    const float bh = bias[h];
#pragma unroll
    for (int i = 0; i < 8; ++i) acc[i] = bh;
    for (int k = 0; k < 256; k += 4) {
        floatx4 w4 = *(const floatx4*)&W[h * 256 + k];
#pragma unroll
        for (int i = 0; i < 8; ++i) {
            floatx4 x4 = *(const floatx4*)&xl[i * 256 + k];
            acc[i] += w4[0] * x4[0] + w4[1] * x4[1] + w4[2] * x4[2] + w4[3] * x4[3];
        }
    }
#pragma unroll
    for (int i = 0; i < 8; ++i) enc[(b0 + i) * 256 + h] = acc[i];
}

// ---------------------------------------------------------------------------
// genc[b][g] = b_ih[g]+b_hh[g] + sum_k enc[b][k] * W_ih[g][128+k]
// grid 512 blocks (128 bgroups x 4 gchunks) x 256 thr
__global__ void k_genc(const float* __restrict__ enc, const float* __restrict__ W_ih,
                       const float* __restrict__ b_ih, const float* __restrict__ b_hh,
                       float* __restrict__ genc) {
    __shared__ float el[8 * 256];
    const int bg = blockIdx.x >> 2;
    const int gc = blockIdx.x & 3;
    const int tid = threadIdx.x;
    const int b0 = bg * 8;
#pragma unroll
    for (int i = 0; i < 8; ++i) el[i * 256 + tid] = enc[(b0 + i) * 256 + tid];
    __syncthreads();
    const int g = gc * 256 + tid;
    float acc[8];
    const float bb = b_ih[g] + b_hh[g];
#pragma unroll
    for (int i = 0; i < 8; ++i) acc[i] = bb;
    for (int k = 0; k < 256; k += 4) {
        floatx4 w4 = *(const floatx4*)&W_ih[g * 384 + 128 + k];
#pragma unroll
        for (int i = 0; i < 8; ++i) {
            floatx4 e4 = *(const floatx4*)&el[i * 256 + k];
            acc[i] += w4[0] * e4[0] + w4[1] * e4[1] + w4[2] * e4[2] + w4[3] * e4[3];
        }
    }
#pragma unroll
    for (int i = 0; i < 8; ++i) genc[(b0 + i) * 1024 + g] = acc[i];
}

// ---------------------------------------------------------------------------
// embW[v][g] = sum_e emb[v][e] * W_ih[g][e]   (e < 128)
// grid 410 blocks x 256 thr (4 g per thread)
__global__ void k_embW(const float* __restrict__ emb, const float* __restrict__ W_ih,
                       float* __restrict__ embW) {
    __shared__ float el[128];
    const int v = blockIdx.x, tid = threadIdx.x;
    if (tid < 128) el[tid] = emb[v * 128 + tid];
    __syncthreads();
    float acc[4] = {0.f, 0.f, 0.f, 0.f};
    for (int k = 0; k < 128; k += 4) {
        floatx4 e4 = *(const floatx4*)&el[k];
#pragma unroll
        for (int j = 0; j < 4; ++j) {
            floatx4 w4 = *(const floatx4*)&W_ih[(tid + 256 * j) * 384 + k];
            acc[j] += w4[0] * e4[0] + w4[1] * e4[1] + w4[2] * e4[2] + w4[3] * e4[3];
        }
    }
#pragma unroll
    for (int j = 0; j < 4; ++j) embW[v * 1024 + tid + 256 * j] = acc[j];
}

// ---------------------------------------------------------------------------
// Cast W_hh / W_fc to bf16 in MFMA B-fragment order:
// frag[((nt*8+kt)*64+lane)*8 + j] = W[n = nt*16+(lane&15)][k = kt*32+(lane>>4)*8+j]
__global__ void k_frag(const float* __restrict__ W_hh, const float* __restrict__ W_fc,
                       short* __restrict__ whh_frag, short* __restrict__ wfc_frag) {
    const int idx = blockIdx.x * 256 + threadIdx.x;
    if (idx < 64 * 8 * 64) {
        const int l = idx & 63, kt = (idx >> 6) & 7, nt = idx >> 9;
        const int g = nt * 16 + (l & 15);
        const int kb = kt * 32 + (l >> 4) * 8;
        short8 o;
#pragma unroll
        for (int j = 0; j < 8; ++j) o[j] = f2bf(W_hh[g * 256 + kb + j]);
        *(short8*)(whh_frag + (size_t)idx * 8) = o;
    } else {
        const int i2 = idx - 64 * 8 * 64;
        if (i2 < NT_FC * 8 * 64) {
            const int l = i2 & 63, kt = (i2 >> 6) & 7, nt = i2 >> 9;
            const int v = nt * 16 + (l & 15);
            const int kb = kt * 32 + (l >> 4) * 8;
            short8 o;
#pragma unroll
            for (int j = 0; j < 8; ++j)
                o[j] = (v < VOC) ? f2bf(W_fc[v * 256 + kb + j]) : (short)0;
            *(short8*)(wfc_frag + (size_t)i2 * 8) = o;
        }
    }
}

// ---------------------------------------------------------------------------
// Persistent LSTM: 64 WGs x 512 thr, each WG owns 16 batch rows for all 99 steps.
// Wave w owns hidden units [w*32, w*32+32) = jtiles {2w, 2w+1}; gates q=0..3 map
// to ntile = q*16 + jtile, so i/f/g/o for a unit land in the same lane slot.
__global__ __launch_bounds__(512, 2) void k_lstm(
    const float* __restrict__ genc, const float* __restrict__ embW,
    const short* __restrict__ whh_frag, const int* __restrict__ targets,
    short* __restrict__ hs) {
    __shared__ short hlds[16 * 264];  // h bf16, [m=batch-local][k=unit], pad 264
    const int tid = threadIdx.x;
    const int w = tid >> 6, lane = tid & 63;
    const int q16 = lane >> 4, l16 = lane & 15;
    const int b0 = blockIdx.x * 16;

    for (int i = tid; i < 16 * 264; i += 512) hlds[i] = 0;

    float c_state[2][4];
#pragma unroll
    for (int jj = 0; jj < 2; ++jj)
#pragma unroll
        for (int r = 0; r < 4; ++r) c_state[jj][r] = 0.f;

    __syncthreads();

    for (int t = 0; t < TSEQ; ++t) {
        // A-fragments: h_prev, shared by all waves
        short8 afrag[8];
#pragma unroll
        for (int kt = 0; kt < 8; ++kt)
            afrag[kt] = *(const short8*)&hlds[l16 * 264 + kt * 32 + q16 * 8];
        __syncthreads();  // everyone has read h before anyone overwrites it

        int tok[4];
#pragma unroll
        for (int r = 0; r < 4; ++r) tok[r] = targets[(b0 + q16 * 4 + r) * 100 + t];

        floatx4 acc[2][4];
#pragma unroll
        for (int jj = 0; jj < 2; ++jj) {
#pragma unroll
            for (int q = 0; q < 4; ++q) {
                floatx4 a = {0.f, 0.f, 0.f, 0.f};
                const int nt = q * 16 + (2 * w + jj);
#pragma unroll
                for (int kt = 0; kt < 8; ++kt) {
                    short8 bfrag = *(const short8*)(whh_frag + ((size_t)(nt * 8 + kt) * 64 + lane) * 8);
                    a = __builtin_amdgcn_mfma_f32_16x16x32_bf16(afrag[kt], bfrag, a, 0, 0, 0);
                }
                acc[jj][q] = a;
            }
        }

        // elementwise LSTM update, all in-lane
#pragma unroll
        for (int jj = 0; jj < 2; ++jj) {
            const int u = w * 32 + jj * 16 + l16;
#pragma unroll
            for (int r = 0; r < 4; ++r) {
                const int b = b0 + q16 * 4 + r;
                const float* gb = genc + (size_t)b * GDIM + u;
                const float* eb = embW + (size_t)tok[r] * GDIM + u;
                float gi = acc[jj][0][r] + gb[0] + eb[0];
                float gf = acc[jj][1][r] + gb[256] + eb[256];
                float gg = acc[jj][2][r] + gb[512] + eb[512];
                float go = acc[jj][3][r] + gb[768] + eb[768];
                float i_ = 1.f / (1.f + expf(-gi));
                float f_ = 1.f / (1.f + expf(-gf));
                float g_ = tanhf(gg);
                float o_ = 1.f / (1.f + expf(-go));
                float c = f_ * c_state[jj][r] + i_ * g_;
                c_state[jj][r] = c;
                float h = o_ * tanhf(c);
                short hb = f2bf(h);
                hlds[(q16 * 4 + r) * 264 + u] = hb;
                hs[((size_t)b * TSEQ + t) * HID + u] = hb;
            }
        }
        __syncthreads();  // h complete before next step's reads
    }
}

// ---------------------------------------------------------------------------
// logits[r][v] = b_fc[v] + sum_k hs[r][k] * W_fc[v][k], r = b*99+t
// grid 1584 blocks x 256 thr (4 waves x 16 rows)
__global__ __launch_bounds__(256, 2) void k_logits(
    const short* __restrict__ hs, const short* __restrict__ wfc_frag,
    const float* __restrict__ b_fc, float* __restrict__ out) {
    const int tid = threadIdx.x;
    const int w = tid >> 6, lane = tid & 63;
    const int q16 = lane >> 4, l16 = lane & 15;
    const long mbase = (long)blockIdx.x * 64 + w * 16;

    short8 afrag[8];
#pragma unroll
    for (int kt = 0; kt < 8; ++kt)
        afrag[kt] = *(const short8*)(hs + (mbase + l16) * HID + kt * 32 + q16 * 8);

#pragma unroll 1
    for (int nt = 0; nt < NT_FC; ++nt) {
        floatx4 a = {0.f, 0.f, 0.f, 0.f};
#pragma unroll
        for (int kt = 0; kt < 8; ++kt) {
            short8 bfrag = *(const short8*)(wfc_frag + ((size_t)(nt * 8 + kt) * 64 + lane) * 8);
            a = __builtin_amdgcn_mfma_f32_16x16x32_bf16(afrag[kt], bfrag, a, 0, 0, 0);
        }
        const int v = nt * 16 + l16;
        if (v < VOC) {
            const float bias = b_fc[v];
#pragma unroll
            for (int r = 0; r < 4; ++r) {
                const long row = mbase + q16 * 4 + r;
                out[row * VOC + v] = a[r] + bias;
            }
        }
    }
}

// ---------------------------------------------------------------------------
extern "C" void kernel_launch(void* const* d_in, const int* in_sizes, int n_in,
                              void* d_out, int out_size, void* d_ws, size_t ws_size,
                              hipStream_t stream) {
    const float* encoder_out = (const float*)d_in[0];
    const int*   targets     = (const int*)d_in[1];
    const float* emb         = (const float*)d_in[2];
    const float* W_enc       = (const float*)d_in[3];
    const float* b_enc       = (const float*)d_in[4];
    const float* W_ih        = (const float*)d_in[5];
    const float* W_hh        = (const float*)d_in[6];
    const float* b_ih        = (const float*)d_in[7];
    const float* b_hh        = (const float*)d_in[8];
    const float* W_fc        = (const float*)d_in[9];
    const float* b_fc        = (const float*)d_in[10];
    float* out = (float*)d_out;

    char* ws = (char*)d_ws;
    float* enc      = (float*)(ws + 0);                    // 1,048,576 B
    float* genc     = (float*)(ws + 1048576);              // 4,194,304 B
    float* embW     = (float*)(ws + 5242880);              // 1,679,360 B
    short* whh_frag = (short*)(ws + 6922240);              //   524,288 B
    short* wfc_frag = (short*)(ws + 7446528);              //   212,992 B
    short* hs       = (short*)(ws + 7659520);              // 51,904,512 B  (~59.5 MB total)

    k_enc<<<128, 256, 0, stream>>>(encoder_out, W_enc, b_enc, enc);
    k_genc<<<512, 256, 0, stream>>>(enc, W_ih, b_ih, b_hh, genc);
    k_embW<<<410, 256, 0, stream>>>(emb, W_ih, embW);
    k_frag<<<180, 256, 0, stream>>>(W_hh, W_fc, whh_frag, wfc_frag);
    k_lstm<<<64, 512, 0, stream>>>(genc, embW, whh_frag, targets, hs);
    k_logits<<<1584, 256, 0, stream>>>(hs, wfc_frag, b_fc, out);
}

// Round 2
// 1323.049 us; speedup vs baseline: 1.1331x; 1.1331x over previous
//
#include <hip/hip_runtime.h>
#include <hip/hip_bf16.h>
#include <stdint.h>
#include <stddef.h>

// Problem dims
#define BATCH 1024
#define TSEQ  99      // SEQ_LEN-1 steps
#define HID   256
#define GDIM  1024    // 4*HID
#define EDIM  128
#define VOC   410
#define NT_FC 26      // ceil(410/16) -> padded 416

typedef __attribute__((ext_vector_type(8))) short short8;
typedef __attribute__((ext_vector_type(4))) float floatx4;

#define LOG2E 1.4426950408889634f

__device__ __forceinline__ short f2bf(float x) {
    union { float f; uint32_t u; } v; v.f = x;
    uint32_t r = (v.u + 0x7fffu + ((v.u >> 16) & 1u)) >> 16;
    return (short)r;
}

__device__ __forceinline__ float fexp2(float x) {
#if __has_builtin(__builtin_amdgcn_exp2f)
    return __builtin_amdgcn_exp2f(x);
#else
    return __exp2f(x);
#endif
}
__device__ __forceinline__ float frcp(float x) {
#if __has_builtin(__builtin_amdgcn_rcpf)
    return __builtin_amdgcn_rcpf(x);
#else
    return 1.f / x;
#endif
}
// sigmoid: exp2 overflow -> inf -> rcp -> 0 (correct limit); no clamp needed
__device__ __forceinline__ float sigm(float x) {
    return frcp(1.f + fexp2(-LOG2E * x));
}
// tanh: clamp to avoid inf/inf NaN; tanh(16) == 1.0f in fp32
__device__ __forceinline__ float tanh_fast(float x) {
    x = fminf(fmaxf(x, -16.f), 16.f);
    float t = fexp2((2.f * LOG2E) * x);
    return (t - 1.f) * frcp(t + 1.f);
}

// ---------------------------------------------------------------------------
// enc[b][h] = b_enc[h] + sum_k encoder_out[b][k] * W_enc[h][k]
__global__ void k_enc(const float* __restrict__ x, const float* __restrict__ W,
                      const float* __restrict__ bias, float* __restrict__ enc) {
    __shared__ float xl[8 * 256];
    const int tid = threadIdx.x;
    const int b0 = blockIdx.x * 8;
#pragma unroll
    for (int i = 0; i < 8; ++i) xl[i * 256 + tid] = x[(b0 + i) * 256 + tid];
    __syncthreads();
    const int h = tid;
    float acc[8];
    const float bh = bias[h];
#pragma unroll
    for (int i = 0; i < 8; ++i) acc[i] = bh;
    for (int k = 0; k < 256; k += 4) {
        floatx4 w4 = *(const floatx4*)&W[h * 256 + k];
#pragma unroll
        for (int i = 0; i < 8; ++i) {
            floatx4 x4 = *(const floatx4*)&xl[i * 256 + k];
            acc[i] += w4[0] * x4[0] + w4[1] * x4[1] + w4[2] * x4[2] + w4[3] * x4[3];
        }
    }
#pragma unroll
    for (int i = 0; i < 8; ++i) enc[(b0 + i) * 256 + h] = acc[i];
}

// ---------------------------------------------------------------------------
// genc[b][g] = b_ih[g]+b_hh[g] + sum_k enc[b][k] * W_ih[g][128+k]
__global__ void k_genc(const float* __restrict__ enc, const float* __restrict__ W_ih,
                       const float* __restrict__ b_ih, const float* __restrict__ b_hh,
                       float* __restrict__ genc) {
    __shared__ float el[8 * 256];
    const int bg = blockIdx.x >> 2;
    const int gc = blockIdx.x & 3;
    const int tid = threadIdx.x;
    const int b0 = bg * 8;
#pragma unroll
    for (int i = 0; i < 8; ++i) el[i * 256 + tid] = enc[(b0 + i) * 256 + tid];
    __syncthreads();
    const int g = gc * 256 + tid;
    float acc[8];
    const float bb = b_ih[g] + b_hh[g];
#pragma unroll
    for (int i = 0; i < 8; ++i) acc[i] = bb;
    for (int k = 0; k < 256; k += 4) {
        floatx4 w4 = *(const floatx4*)&W_ih[g * 384 + 128 + k];
#pragma unroll
        for (int i = 0; i < 8; ++i) {
            floatx4 e4 = *(const floatx4*)&el[i * 256 + k];
            acc[i] += w4[0] * e4[0] + w4[1] * e4[1] + w4[2] * e4[2] + w4[3] * e4[3];
        }
    }
#pragma unroll
    for (int i = 0; i < 8; ++i) genc[(b0 + i) * 1024 + g] = acc[i];
}

// ---------------------------------------------------------------------------
// embW[v][g] = sum_e emb[v][e] * W_ih[g][e]   (e < 128)
__global__ void k_embW(const float* __restrict__ emb, const float* __restrict__ W_ih,
                       float* __restrict__ embW) {
    __shared__ float el[128];
    const int v = blockIdx.x, tid = threadIdx.x;
    if (tid < 128) el[tid] = emb[v * 128 + tid];
    __syncthreads();
    float acc[4] = {0.f, 0.f, 0.f, 0.f};
    for (int k = 0; k < 128; k += 4) {
        floatx4 e4 = *(const floatx4*)&el[k];
#pragma unroll
        for (int j = 0; j < 4; ++j) {
            floatx4 w4 = *(const floatx4*)&W_ih[(tid + 256 * j) * 384 + k];
            acc[j] += w4[0] * e4[0] + w4[1] * e4[1] + w4[2] * e4[2] + w4[3] * e4[3];
        }
    }
#pragma unroll
    for (int j = 0; j < 4; ++j) embW[v * 1024 + tid + 256 * j] = acc[j];
}

// ---------------------------------------------------------------------------
// Cast W_hh / W_fc to bf16 in MFMA B-fragment order:
// frag[((nt*8+kt)*64+lane)*8 + j] = W[n = nt*16+(lane&15)][k = kt*32+(lane>>4)*8+j]
__global__ void k_frag(const float* __restrict__ W_hh, const float* __restrict__ W_fc,
                       short* __restrict__ whh_frag, short* __restrict__ wfc_frag) {
    const int idx = blockIdx.x * 256 + threadIdx.x;
    if (idx < 64 * 8 * 64) {
        const int l = idx & 63, kt = (idx >> 6) & 7, nt = idx >> 9;
        const int g = nt * 16 + (l & 15);
        const int kb = kt * 32 + (l >> 4) * 8;
        short8 o;
#pragma unroll
        for (int j = 0; j < 8; ++j) o[j] = f2bf(W_hh[g * 256 + kb + j]);
        *(short8*)(whh_frag + (size_t)idx * 8) = o;
    } else {
        const int i2 = idx - 64 * 8 * 64;
        if (i2 < NT_FC * 8 * 64) {
            const int l = i2 & 63, kt = (i2 >> 6) & 7, nt = i2 >> 9;
            const int v = nt * 16 + (l & 15);
            const int kb = kt * 32 + (l >> 4) * 8;
            short8 o;
#pragma unroll
            for (int j = 0; j < 8; ++j)
                o[j] = (v < VOC) ? f2bf(W_fc[v * 256 + kb + j]) : (short)0;
            *(short8*)(wfc_frag + (size_t)i2 * 8) = o;
        }
    }
}

// ---------------------------------------------------------------------------
// Persistent LSTM: 64 WGs x 512 thr, each WG owns 16 batch rows for all 99 steps.
// h double-buffered in LDS in A-fragment order: hbuf[buf][(u>>3)*16 + row]*8 + (u&7)
// -> ds_read_b128 for A-fragments is perfectly sequential (0 bank conflicts),
// and only ONE __syncthreads per step is needed.
__global__ __launch_bounds__(512, 2) void k_lstm(
    const float* __restrict__ genc, const float* __restrict__ embW,
    const short* __restrict__ whh_frag, const int* __restrict__ targets,
    short* __restrict__ hs) {
    __shared__ short hbuf[2][4096];  // 2 x 8KB
    const int tid = threadIdx.x;
    const int w = tid >> 6, lane = tid & 63;
    const int q16 = lane >> 4, l16 = lane & 15;
    const int b0 = blockIdx.x * 16;

    for (int i = tid; i < 4096; i += 512) hbuf[0][i] = 0;

    float c_state[2][4];
#pragma unroll
    for (int jj = 0; jj < 2; ++jj)
#pragma unroll
        for (int r = 0; r < 4; ++r) c_state[jj][r] = 0.f;

    // token prefetch for t=0
    int tok[4];
#pragma unroll
    for (int r = 0; r < 4; ++r) tok[r] = targets[(b0 + q16 * 4 + r) * 100];

    __syncthreads();

    for (int t = 0; t < TSEQ; ++t) {
        // prefetch next step's tokens (col t+1 <= 99 always in bounds)
        int tokn[4];
#pragma unroll
        for (int r = 0; r < 4; ++r)
            tokn[r] = targets[(b0 + q16 * 4 + r) * 100 + t + 1];

        // gate-bias prefetch: ge = embW[tok] + genc  (issued before MFMA phase
        // so the L2 latency hides under the weight-stream/MFMA work)
        float ge[2][4][4];
#pragma unroll
        for (int jj = 0; jj < 2; ++jj) {
            const int u = w * 32 + jj * 16 + l16;
#pragma unroll
            for (int q = 0; q < 4; ++q) {
#pragma unroll
                for (int r = 0; r < 4; ++r) {
                    const int b = b0 + q16 * 4 + r;
                    ge[jj][q][r] = embW[(size_t)tok[r] * GDIM + q * 256 + u]
                                 + genc[(size_t)b * GDIM + q * 256 + u];
                }
            }
        }

        // A-fragments from LDS (conflict-free b128 reads)
        const short* hb = hbuf[t & 1];
        short8 afrag[8];
#pragma unroll
        for (int kt = 0; kt < 8; ++kt)
            afrag[kt] = *(const short8*)&hb[((kt * 4 + q16) * 16 + l16) * 8];

        // MFMA: gates = h_prev @ W_hh^T  (weight stream nontemporal: it is
        // 512KB/step/CU and can never live in the 32KB L1)
        floatx4 acc[2][4];
#pragma unroll
        for (int jj = 0; jj < 2; ++jj) {
#pragma unroll
            for (int q = 0; q < 4; ++q) {
                floatx4 a = {0.f, 0.f, 0.f, 0.f};
                const int nt = q * 16 + 2 * w + jj;
#pragma unroll
                for (int kt = 0; kt < 8; ++kt) {
                    short8 bfrag = __builtin_nontemporal_load(
                        (const short8*)(whh_frag + ((size_t)(nt * 8 + kt) * 64 + lane) * 8));
                    a = __builtin_amdgcn_mfma_f32_16x16x32_bf16(afrag[kt], bfrag, a, 0, 0, 0);
                }
                acc[jj][q] = a;
            }
        }

        // elementwise LSTM update, all in-lane
        short* hn = hbuf[(t + 1) & 1];
#pragma unroll
        for (int jj = 0; jj < 2; ++jj) {
            const int u = w * 32 + jj * 16 + l16;
#pragma unroll
            for (int r = 0; r < 4; ++r) {
                const int b = b0 + q16 * 4 + r;
                float gi = acc[jj][0][r] + ge[jj][0][r];
                float gf = acc[jj][1][r] + ge[jj][1][r];
                float gg = acc[jj][2][r] + ge[jj][2][r];
                float go = acc[jj][3][r] + ge[jj][3][r];
                float i_ = sigm(gi);
                float f_ = sigm(gf);
                float g_ = tanh_fast(gg);
                float o_ = sigm(go);
                float c = f_ * c_state[jj][r] + i_ * g_;
                c_state[jj][r] = c;
                float h = o_ * tanh_fast(c);
                short hbv = f2bf(h);
                hn[((w * 4 + jj * 2 + (l16 >> 3)) * 16 + (q16 * 4 + r)) * 8 + (l16 & 7)] = hbv;
                hs[((size_t)b * TSEQ + t) * HID + u] = hbv;
            }
        }
#pragma unroll
        for (int r = 0; r < 4; ++r) tok[r] = tokn[r];
        __syncthreads();  // h(t) fully in hbuf[(t+1)&1] before step t+1 reads it
    }
}

// ---------------------------------------------------------------------------
// logits[r][v] = b_fc[v] + sum_k hs[r][k] * W_fc[v][k], r = b*99+t
__global__ __launch_bounds__(256, 2) void k_logits(
    const short* __restrict__ hs, const short* __restrict__ wfc_frag,
    const float* __restrict__ b_fc, float* __restrict__ out) {
    const int tid = threadIdx.x;
    const int w = tid >> 6, lane = tid & 63;
    const int q16 = lane >> 4, l16 = lane & 15;
    const long mbase = (long)blockIdx.x * 64 + w * 16;

    short8 afrag[8];
#pragma unroll
    for (int kt = 0; kt < 8; ++kt)
        afrag[kt] = *(const short8*)(hs + (mbase + l16) * HID + kt * 32 + q16 * 8);

#pragma unroll 1
    for (int nt = 0; nt < NT_FC; ++nt) {
        floatx4 a = {0.f, 0.f, 0.f, 0.f};
#pragma unroll
        for (int kt = 0; kt < 8; ++kt) {
            short8 bfrag = *(const short8*)(wfc_frag + ((size_t)(nt * 8 + kt) * 64 + lane) * 8);
            a = __builtin_amdgcn_mfma_f32_16x16x32_bf16(afrag[kt], bfrag, a, 0, 0, 0);
        }
        const int v = nt * 16 + l16;
        if (v < VOC) {
            const float bias = b_fc[v];
#pragma unroll
            for (int r = 0; r < 4; ++r) {
                const long row = mbase + q16 * 4 + r;
                out[row * VOC + v] = a[r] + bias;
            }
        }
    }
}

// ---------------------------------------------------------------------------
extern "C" void kernel_launch(void* const* d_in, const int* in_sizes, int n_in,
                              void* d_out, int out_size, void* d_ws, size_t ws_size,
                              hipStream_t stream) {
    const float* encoder_out = (const float*)d_in[0];
    const int*   targets     = (const int*)d_in[1];
    const float* emb         = (const float*)d_in[2];
    const float* W_enc       = (const float*)d_in[3];
    const float* b_enc       = (const float*)d_in[4];
    const float* W_ih        = (const float*)d_in[5];
    const float* W_hh        = (const float*)d_in[6];
    const float* b_ih        = (const float*)d_in[7];
    const float* b_hh        = (const float*)d_in[8];
    const float* W_fc        = (const float*)d_in[9];
    const float* b_fc        = (const float*)d_in[10];
    float* out = (float*)d_out;

    char* ws = (char*)d_ws;
    float* enc      = (float*)(ws + 0);                    // 1,048,576 B
    float* genc     = (float*)(ws + 1048576);              // 4,194,304 B
    float* embW     = (float*)(ws + 5242880);              // 1,679,360 B
    short* whh_frag = (short*)(ws + 6922240);              //   524,288 B
    short* wfc_frag = (short*)(ws + 7446528);              //   212,992 B
    short* hs       = (short*)(ws + 7659520);              // 51,904,512 B

    k_enc<<<128, 256, 0, stream>>>(encoder_out, W_enc, b_enc, enc);
    k_genc<<<512, 256, 0, stream>>>(enc, W_ih, b_ih, b_hh, genc);
    k_embW<<<410, 256, 0, stream>>>(emb, W_ih, embW);
    k_frag<<<180, 256, 0, stream>>>(W_hh, W_fc, whh_frag, wfc_frag);
    k_lstm<<<64, 512, 0, stream>>>(genc, embW, whh_frag, targets, hs);
    k_logits<<<1584, 256, 0, stream>>>(hs, wfc_frag, b_fc, out);
}